// Round 11
// baseline (1068.541 us; speedup 1.0000x reference)
//
#include <hip/hip_runtime.h>
#include <hip/hip_bf16.h>
#include <cstdint>
#include <cstddef>

// Model: B=1024, S=60, CIN=25, D=256, H=256, T=S+2=62
// Inputs fp32, output fp32; internal bf16 activations/weights, fp32 accum.
//
// Round-22 = R21 (970us verified; resident-Whh proven order-safe, absmax
// bit-identical) + dose increase 4 -> 6 resident blocks (96 VGPR pinned,
// total ~148 vs the 256 cap; R20's failure band started ~216). Streamed
// weights drop another 2 blocks/wave: L1 655->590 KB/step, L0 393->327.
// S = KB-6 is == 2 (mod 4), so the streamed dist-2 pipeline gets a 6-block
// epilogue (blocks S-6..S-1); block order 0..KB-1 and therefore fp32
// accumulation order remain bit-identical.
// Session rules: weights NEVER via LDS (R12/R16 3x collapse); exchange
// loose vs writes (R15 storm); RELAXED handshake only (R19); one change
// per round; VGPR gate ~<200.

typedef __attribute__((ext_vector_type(8))) short short8;
typedef __attribute__((ext_vector_type(4))) float floatx4;

#define BATCH 1024
#define TSTEPS 62

__device__ __forceinline__ float bf2f(short s) {
    union { unsigned u; float f; } v;
    v.u = ((unsigned)(unsigned short)s) << 16;
    return v.f;
}
__device__ __forceinline__ short f2bf(float f) {
    union { float f; unsigned u; } v; v.f = f;
    unsigned r = (v.u + 0x7fffu + ((v.u >> 16) & 1u)) >> 16;  // RNE
    return (short)r;
}
__device__ __forceinline__ float sigf(float x) {
    return __builtin_amdgcn_rcpf(1.0f + __expf(-x));
}
__device__ __forceinline__ float tanhf_fast(float x) {
    return 2.0f * __builtin_amdgcn_rcpf(1.0f + __expf(-2.0f * x)) - 1.0f;
}

// async 16B/lane global->LDS (LDS dest = uniform base + lane*16)
__device__ __forceinline__ void load_lds16(const short* g, short* l) {
    __builtin_amdgcn_global_load_lds(
        (const __attribute__((address_space(1))) void*)g,
        (__attribute__((address_space(3))) void*)l, 16, 0, 0);
}

// ------------- repack [Wih|Whh] into unit-split wave-blocked layout --------
// dst idx = ((((dh*8 + w)*KB + kb)*4 + g)*64 + lane)*8 + j
//   dh = dir*2 + half
//   row = g*256 + half*128 + w*16 + (lane&15)
//   k   = kb*32 + (lane>>4)*8 + j
__global__ __launch_bounds__(256) void repack_kernel(
    const float* __restrict__ Wih, const float* __restrict__ Whh,
    short* __restrict__ Wp, int XI)
{
    const int KB = (XI + 256) / 32;
    int idx = blockIdx.x * 256 + threadIdx.x;
    if (idx >= 8 * KB * 8192) return;
    int j    = idx & 7;
    int lane = (idx >> 3) & 63;
    int g    = (idx >> 9) & 3;
    int rem  = idx >> 11;
    int kb   = rem % KB;
    int rem2 = rem / KB;
    int w    = rem2 & 7;
    int dh   = rem2 >> 3;       // 0..3
    int dir  = dh >> 1;
    int half = dh & 1;
    int row  = g * 256 + half * 128 + w * 16 + (lane & 15);
    int k    = kb * 32 + (lane >> 4) * 8 + j;
    float v = (k < XI) ? Wih[((size_t)dir * 1024 + row) * XI + k]
                       : Whh[((size_t)dir * 1024 + row) * 256 + (k - XI)];
    Wp[idx] = f2bf(v);
}

// ---------------- embed: seq[t][b][d], row stride 264 ----------------------
__global__ __launch_bounds__(256) void embed_kernel(
    const float* __restrict__ x, const float* __restrict__ Wg,
    const float* __restrict__ bg, const float* __restrict__ Wl,
    const float* __restrict__ bl, short* __restrict__ seq)
{
    const int b = blockIdx.x;
    const int d = threadIdx.x;  // 256 = D
    __shared__ float xs[1500];
    for (int i = d; i < 1500; i += 256) xs[i] = x[(size_t)b * 1500 + i];
    __syncthreads();

    float g = bg[d];
#pragma unroll
    for (int c = 0; c < 16; ++c) g += xs[9 + c] * Wg[d * 16 + c];
    short gb = f2bf(g);
    seq[((size_t)0 * BATCH + b) * 264 + d] = gb;
    seq[((size_t)61 * BATCH + b) * 264 + d] = gb;

    for (int t = 0; t < 60; ++t) {
        float v = bl[d];
#pragma unroll
        for (int c = 0; c < 9; ++c) v += xs[t * 25 + c] * Wl[d * 9 + c];
        seq[((size_t)(t + 1) * BATCH + b) * 264 + d] = f2bf(v);
    }
}

// ---------------- persistent biLSTM layer (unit-split, 256 WGs) ------------
#define LOADW(BUF, kbq)                                                          \
    {                                                                            \
        _Pragma("unroll")                                                        \
        for (int g = 0; g < 4; ++g)                                              \
            BUF[g] = *reinterpret_cast<const short8*>(                           \
                wpb + (size_t)(kbq) * 2048 + g * 512);                           \
    }
#define LOADA(DST, kbg)                                                          \
    {                                                                            \
        DST = ((kbg) < XB)                                                       \
            ? *reinterpret_cast<const short8*>(xs_cur + lr * (XI + 8) + (kbg) * 32 + quad * 8) \
            : *reinterpret_cast<const short8*>(&h_lds[lr][((kbg) - XB) * 32 + quad * 8]); \
    }
#define MFMA4(AV, BUF)                                                           \
    {                                                                            \
        _Pragma("unroll")                                                        \
        for (int g = 0; g < 4; ++g)                                              \
            acc[g] = __builtin_amdgcn_mfma_f32_16x16x32_bf16(                    \
                AV, BUF[g], acc[g], 0, 0, 0);                                    \
    }
#define MFMA4R(AV, i)                                                            \
    {                                                                            \
        _Pragma("unroll")                                                        \
        for (int g = 0; g < 4; ++g)                                              \
            acc[g] = __builtin_amdgcn_mfma_f32_16x16x32_bf16(                    \
                AV, RW[i][g], acc[g], 0, 0, 0);                                  \
    }
// stage one 16-row X tile (XI cols of XSTR-stride rows): 8 waves x 2 rows
#define STAGE(BUFP, T1)                                                          \
    {                                                                            \
        const short* xtb = X + ((size_t)(T1) * BATCH + bbase) * XSTR;            \
        _Pragma("unroll")                                                        \
        for (int i = 0; i < 2; ++i) {                                            \
            int row = wv * 2 + i;                                                \
            if (XI == 512 || lane < 32)                                          \
                load_lds16(xtb + (size_t)row * XSTR + lane * 8,                  \
                           (BUFP) + row * (XI + 8));                             \
        }                                                                        \
    }

template <int KK, int XSTR, int OSTR>  // KK=512: XI=256 (layer0); KK=768: XI=512
__global__ __launch_bounds__(512, 2) void lstm_fused_kernel(
    const short* __restrict__ X,      // (62,1024,XSTR) bf16, first XI cols used
    const short* __restrict__ Wcat,   // unit-split wave-blocked [Wih|Whh]
    const float* __restrict__ bih, const float* __restrict__ bhh,
    short* __restrict__ Hout,         // (62,1024,OSTR); dir d -> cols [256d,..)
    int* __restrict__ flags)          // 128 pairs x 2 halves, zeroed pre-launch
{
    constexpr int XI = KK - 256;
    constexpr int KB = KK / 32;   // 16 or 24
    constexpr int XB = XI / 32;   // 8 or 16
    constexpr int S  = KB - 6;    // streamed blocks 0..S-1 (10 or 18);
                                  // resident S..KB-1 (6 blocks, 96 VGPR)

    const int wg    = blockIdx.x;     // 256 = (2 halves) x (2 dirs x 64 tiles)
    const int half  = wg >> 7;
    const int pair  = wg & 127;       // dir*64 + tile
    const int dir   = pair >> 6;
    const int bbase = (pair & 63) * 16;
    const int tid   = threadIdx.x;
    const int wv    = tid >> 6;       // 0..7
    const int lane  = tid & 63;
    const int quad  = lane >> 4;
    const int lr    = lane & 15;

    __shared__ __align__(16) short h_lds[16][264];
    __shared__ __align__(16) short x_stage[2][16 * (XI + 8)];
    __shared__ float bias_sh[1024];
    for (int i = tid; i < 16 * 264; i += 512) (&h_lds[0][0])[i] = 0;
    for (int i = tid; i < 1024; i += 512)
        bias_sh[i] = bih[dir * 1024 + i] + bhh[dir * 1024 + i];

    // per-wave weight stream: KB blocks of 2048 shorts (4 gates x 512)
    const short* wpb = Wcat +
        ((size_t)((dir * 2 + half) * 8 + wv) * KB) * 2048 + lane * 8;

    // register-resident Whh tail: blocks KB-6..KB-1, loaded once (96 VGPR)
    short8 RW[6][4];
#pragma unroll
    for (int i = 0; i < 6; ++i)
#pragma unroll
        for (int g = 0; g < 4; ++g)
            RW[i][g] = *reinterpret_cast<const short8*>(
                wpb + (size_t)(S + i) * 2048 + g * 512);

    const int colC = (half ^ 1) * 128;
    const int myf = (pair << 1) | half;
    const int paf = (pair << 1) | (half ^ 1);

    float c_st[4];
#pragma unroll
    for (int r = 0; r < 4; ++r) c_st[r] = 0.0f;

    // prologue: stage X[t0] into buffer 0 (drained by the barrier below)
    {
        const int t0 = dir ? (TSTEPS - 1) : 0;
        STAGE(&x_stage[0][0], t0);
    }
    __syncthreads();

    for (int st = 0; st < TSTEPS; ++st) {
        const int t = dir ? (TSTEPS - 1 - st) : st;
        if (st + 1 < TSTEPS) {
            const int t1 = dir ? (TSTEPS - 2 - st) : (st + 1);
            STAGE(&x_stage[(st + 1) & 1][0], t1);
        }
        const short* xs_cur = &x_stage[st & 1][0];

        floatx4 acc[4];
#pragma unroll
        for (int i = 0; i < 4; ++i) acc[i] = (floatx4){0.f, 0.f, 0.f, 0.f};

        // streamed part (blocks 0..S-1), dist-2 register pipeline.
        // S == 2 (mod 4): main loop covers blocks 0..S-7, epilogue S-6..S-1.
        short8 W0[4], W1[4], Y0[4], Y1[4], a0, a1;
        LOADW(W0, 0);
        LOADW(W1, 1);
        LOADA(a0, 0);
#pragma unroll 1
        for (int kb = 0; kb < S - 6; kb += 4) {
            LOADW(Y0, kb + 2); LOADA(a1, kb + 1); MFMA4(a0, W0);
            LOADW(Y1, kb + 3); LOADA(a0, kb + 2); MFMA4(a1, W1);
            LOADW(W0, kb + 4); LOADA(a1, kb + 3); MFMA4(a0, Y0);
            LOADW(W1, kb + 5); LOADA(a0, kb + 4); MFMA4(a1, Y1);
        }
        // entering: W0 = blk S-6, W1 = blk S-5, a0 = A(S-6)
        LOADW(Y0, S - 4); LOADA(a1, S - 5); MFMA4(a0, W0);  // S-6
        LOADW(Y1, S - 3); LOADA(a0, S - 4); MFMA4(a1, W1);  // S-5
        LOADW(W0, S - 2); LOADA(a1, S - 3); MFMA4(a0, Y0);  // S-4
        LOADW(W1, S - 1); LOADA(a0, S - 2); MFMA4(a1, Y1);  // S-3
        LOADA(a1, S - 1); MFMA4(a0, W0);                    // S-2
        MFMA4(a1, W1);                                      // S-1

        // resident tail (blocks S..KB-1): zero weight loads
        LOADA(a0, S + 0);
        LOADA(a1, S + 1); MFMA4R(a0, 0);
        LOADA(a0, S + 2); MFMA4R(a1, 1);
        LOADA(a1, S + 3); MFMA4R(a0, 2);
        LOADA(a0, S + 4); MFMA4R(a1, 3);
        LOADA(a1, S + 5); MFMA4R(a0, 4);
        MFMA4R(a1, 5);

        __syncthreads();  // (1) all h_lds / x_stage reads of this step done

        // cell update -> own h_lds columns (all 4 gates thread-local)
        {
            const int unit = half * 128 + wv * 16 + lr;
            const float bi  = bias_sh[0 * 256 + unit];
            const float bf_ = bias_sh[1 * 256 + unit];
            const float bg_ = bias_sh[2 * 256 + unit];
            const float bo_ = bias_sh[3 * 256 + unit];
#pragma unroll
            for (int r = 0; r < 4; ++r) {
                float iv = acc[0][r] + bi;
                float fv = acc[1][r] + bf_;
                float gv = acc[2][r] + bg_;
                float ov = acc[3][r] + bo_;
                float c = sigf(fv) * c_st[r] + sigf(iv) * tanhf_fast(gv);
                c_st[r] = c;
                float h = sigf(ov) * tanhf_fast(c);
                h_lds[quad * 4 + r][unit] = f2bf(h);
            }
        }
        __syncthreads();  // (2) own half complete in h_lds

        // own-half writeback: coalesced agent-scope 8B stores (partner reads)
        {
            const int row = tid >> 5, c4 = tid & 31;
            unsigned long long v = *reinterpret_cast<const unsigned long long*>(
                &h_lds[row][half * 128 + c4 * 4]);
            __hip_atomic_store(
                reinterpret_cast<unsigned long long*>(
                    Hout + ((size_t)t * BATCH + bbase + row) * OSTR +
                    dir * 256 + half * 128) + c4,
                v, __ATOMIC_RELAXED, __HIP_MEMORY_SCOPE_AGENT);
        }
        __syncthreads();  // (3) stores drained (vmcnt 0 at coherence point)
                          //     -> flag may be posted RELAXED

        if (st + 1 < TSTEPS) {
            if (tid == 0) {
                __hip_atomic_store(&flags[myf], st + 1, __ATOMIC_RELAXED,
                                   __HIP_MEMORY_SCOPE_AGENT);
                while (__hip_atomic_load(&flags[paf], __ATOMIC_RELAXED,
                                         __HIP_MEMORY_SCOPE_AGENT) <= st)
                    __builtin_amdgcn_s_sleep(1);
            }
            __syncthreads();  // (4) partner h(t) at coherence point

            // pull partner half into h_lds
            {
                const int row = tid >> 5, c4 = tid & 31;
                unsigned long long v = __hip_atomic_load(
                    reinterpret_cast<const unsigned long long*>(
                        Hout + ((size_t)t * BATCH + bbase + row) * OSTR +
                        dir * 256 + colC) + c4,
                    __ATOMIC_RELAXED, __HIP_MEMORY_SCOPE_AGENT);
                *reinterpret_cast<unsigned long long*>(
                    &h_lds[row][colC + c4 * 4]) = v;
            }
            __syncthreads();  // (5) h_lds complete for next step
        }
    }
}

// ---------------- heads (fp32 output; h1 row stride 512) -------------------
__global__ __launch_bounds__(256) void lout_kernel(
    const short* __restrict__ h1, const float* __restrict__ Wlp,
    const float* __restrict__ blp, float* __restrict__ out)
{
    __shared__ float wl[6 * 512];
    for (int i = threadIdx.x; i < 6 * 512; i += 256) wl[i] = Wlp[i];
    __syncthreads();

    int idx = blockIdx.x * 256 + threadIdx.x;
    if (idx >= BATCH * 60) return;
    int b = idx & (BATCH - 1);
    int s = idx >> 10;
    const short* hrow = h1 + ((size_t)(s + 1) * BATCH + b) * 512;

    float acc[6];
#pragma unroll
    for (int j = 0; j < 6; ++j) acc[j] = blp[j];
    for (int k = 0; k < 512; k += 8) {
        short8 hv = *reinterpret_cast<const short8*>(hrow + k);
#pragma unroll
        for (int e = 0; e < 8; ++e) {
            float h = bf2f(hv[e]);
#pragma unroll
            for (int j = 0; j < 6; ++j) acc[j] += h * wl[j * 512 + k + e];
        }
    }
    float* orow = out + ((size_t)b * 60 + s) * 14;
#pragma unroll
    for (int j = 0; j < 6; ++j) orow[j] = acc[j];
}

__global__ __launch_bounds__(256) void gout_kernel(
    const short* __restrict__ h1, const float* __restrict__ Wgp,
    const float* __restrict__ bgp, float* __restrict__ out)
{
    __shared__ float wg[8 * 1024];
    for (int i = threadIdx.x; i < 8 * 1024; i += 256) wg[i] = Wgp[i];
    __syncthreads();

    int b = blockIdx.x * 256 + threadIdx.x;
    if (b >= BATCH) return;
    const short* ha = h1 + (size_t)b * 512;
    const short* hb = h1 + ((size_t)61 * BATCH + b) * 512;

    float acc[8];
#pragma unroll
    for (int j = 0; j < 8; ++j) acc[j] = bgp[j];
    for (int k = 0; k < 512; k += 8) {
        short8 h1v = *reinterpret_cast<const short8*>(ha + k);
        short8 h2v = *reinterpret_cast<const short8*>(hb + k);
#pragma unroll
        for (int e = 0; e < 8; ++e) {
            float v1 = bf2f(h1v[e]);
            float v2 = bf2f(h2v[e]);
#pragma unroll
            for (int j = 0; j < 8; ++j) {
                acc[j] += v1 * wg[j * 1024 + k + e];
                acc[j] += v2 * wg[j * 1024 + 512 + k + e];
            }
        }
    }
    for (int s = 0; s < 60; ++s) {
        float* orow = out + ((size_t)b * 60 + s) * 14 + 6;
#pragma unroll
        for (int j = 0; j < 8; ++j) orow[j] = acc[j];
    }
}

// ---------------- launch ---------------------------------------------------
extern "C" void kernel_launch(void* const* d_in, const int* in_sizes, int n_in,
                              void* d_out, int out_size, void* d_ws, size_t ws_size,
                              hipStream_t stream)
{
    const float* x    = (const float*)d_in[0];
    const float* Wg   = (const float*)d_in[1];
    const float* bg   = (const float*)d_in[2];
    const float* Wl   = (const float*)d_in[3];
    const float* bl   = (const float*)d_in[4];
    const float* Wih0 = (const float*)d_in[5];
    const float* Whh0 = (const float*)d_in[6];
    const float* bih0 = (const float*)d_in[7];
    const float* bhh0 = (const float*)d_in[8];
    const float* Wih1 = (const float*)d_in[9];
    const float* Whh1 = (const float*)d_in[10];
    const float* bih1 = (const float*)d_in[11];
    const float* bhh1 = (const float*)d_in[12];
    const float* Wgp  = (const float*)d_in[13];
    const float* bgp  = (const float*)d_in[14];
    const float* Wlp  = (const float*)d_in[15];
    const float* blp  = (const float*)d_in[16];
    float* out = (float*)d_out;

    const size_t seq_e = (size_t)TSTEPS * BATCH * 264;  // 16,760,832 (stride 264)
    const size_t h0_e  = (size_t)TSTEPS * BATCH * 520;  // 33,013,760 (stride 520)
    const size_t h1_e  = (size_t)TSTEPS * BATCH * 512;  // 32,505,856 (stride 512)
    const size_t cat_e = 8 * 24 * 8192;                 //  1,572,864 (shared, max)
    const size_t cat0_n = 8 * 16 * 8192;                //  layer0 repack count

    short* seq = (short*)d_ws;
    short* h0  = seq + seq_e;
    short* h1  = h0 + h0_e;
    short* cat = h1 + h1_e;
    int*   flags = (int*)(cat + cat_e);                 // 2 layers x 256 ints
    const size_t need = (seq_e + h0_e + h1_e + cat_e) * sizeof(short) + 2048;
    if (ws_size < need) return;

    hipMemsetAsync(flags, 0, 2 * 256 * sizeof(int), stream);

    embed_kernel<<<BATCH, 256, 0, stream>>>(x, Wg, bg, Wl, bl, seq);

    repack_kernel<<<(int)((cat0_n + 255) / 256), 256, 0, stream>>>(Wih0, Whh0, cat, 256);
    lstm_fused_kernel<512, 264, 520><<<256, 512, 0, stream>>>(seq, cat, bih0, bhh0, h0, flags);

    repack_kernel<<<(int)((cat_e + 255) / 256), 256, 0, stream>>>(Wih1, Whh1, cat, 512);
    lstm_fused_kernel<768, 520, 512><<<256, 512, 0, stream>>>(h0, cat, bih1, bhh1, h1, flags + 256);

    lout_kernel<<<(BATCH * 60 + 255) / 256, 256, 0, stream>>>(h1, Wlp, blp, out);
    gout_kernel<<<(BATCH + 255) / 256, 256, 0, stream>>>(h1, Wgp, bgp, out);
}

// Round 12
// 952.115 us; speedup vs baseline: 1.1223x; 1.1223x over previous
//
#include <hip/hip_runtime.h>
#include <hip/hip_bf16.h>
#include <cstdint>
#include <cstddef>

// Model: B=1024, S=60, CIN=25, D=256, H=256, T=S+2=62
// Inputs fp32, output fp32; internal bf16 activations/weights, fp32 accum.
//
// Round-23 = R21 (970us verified; 4 resident Whh blocks -- the proven dose:
// 6 regressed via broken L2 weight residency (R22 FETCH 104->190MB), 8
// miscompiled (R20)) + ONE isolated change to the exchange tail:
//   PER-WAVE handshake: post (tid0, after the drain barrier -- timing
//   identical to R14/R21) -> each wave's lane0 polls the partner flag ->
//   the wave immediately pulls its own 2 rows (in-order issue: pulls retire
//   after the poll load) -> ds_write -> ONE trailing barrier. Removes
//   barrier (4) and the tid0 poll serialization from every step.
//   Flags padded to 64B each (16 ints) -- required so 8x pollers don't
//   false-share cache lines at the coherence point.
// Session rules: weights NEVER via LDS (R12/R16 3x collapse); exchange
// loose vs writes (R15 storm); RELAXED handshake only (R19); one change
// per round; VGPR gate <200; resident dose stays at 4.

typedef __attribute__((ext_vector_type(8))) short short8;
typedef __attribute__((ext_vector_type(4))) float floatx4;

#define BATCH 1024
#define TSTEPS 62

__device__ __forceinline__ float bf2f(short s) {
    union { unsigned u; float f; } v;
    v.u = ((unsigned)(unsigned short)s) << 16;
    return v.f;
}
__device__ __forceinline__ short f2bf(float f) {
    union { float f; unsigned u; } v; v.f = f;
    unsigned r = (v.u + 0x7fffu + ((v.u >> 16) & 1u)) >> 16;  // RNE
    return (short)r;
}
__device__ __forceinline__ float sigf(float x) {
    return __builtin_amdgcn_rcpf(1.0f + __expf(-x));
}
__device__ __forceinline__ float tanhf_fast(float x) {
    return 2.0f * __builtin_amdgcn_rcpf(1.0f + __expf(-2.0f * x)) - 1.0f;
}

// async 16B/lane global->LDS (LDS dest = uniform base + lane*16)
__device__ __forceinline__ void load_lds16(const short* g, short* l) {
    __builtin_amdgcn_global_load_lds(
        (const __attribute__((address_space(1))) void*)g,
        (__attribute__((address_space(3))) void*)l, 16, 0, 0);
}

// ------------- repack [Wih|Whh] into unit-split wave-blocked layout --------
// dst idx = ((((dh*8 + w)*KB + kb)*4 + g)*64 + lane)*8 + j
//   dh = dir*2 + half
//   row = g*256 + half*128 + w*16 + (lane&15)
//   k   = kb*32 + (lane>>4)*8 + j
__global__ __launch_bounds__(256) void repack_kernel(
    const float* __restrict__ Wih, const float* __restrict__ Whh,
    short* __restrict__ Wp, int XI)
{
    const int KB = (XI + 256) / 32;
    int idx = blockIdx.x * 256 + threadIdx.x;
    if (idx >= 8 * KB * 8192) return;
    int j    = idx & 7;
    int lane = (idx >> 3) & 63;
    int g    = (idx >> 9) & 3;
    int rem  = idx >> 11;
    int kb   = rem % KB;
    int rem2 = rem / KB;
    int w    = rem2 & 7;
    int dh   = rem2 >> 3;       // 0..3
    int dir  = dh >> 1;
    int half = dh & 1;
    int row  = g * 256 + half * 128 + w * 16 + (lane & 15);
    int k    = kb * 32 + (lane >> 4) * 8 + j;
    float v = (k < XI) ? Wih[((size_t)dir * 1024 + row) * XI + k]
                       : Whh[((size_t)dir * 1024 + row) * 256 + (k - XI)];
    Wp[idx] = f2bf(v);
}

// ---------------- embed: seq[t][b][d], row stride 264 ----------------------
__global__ __launch_bounds__(256) void embed_kernel(
    const float* __restrict__ x, const float* __restrict__ Wg,
    const float* __restrict__ bg, const float* __restrict__ Wl,
    const float* __restrict__ bl, short* __restrict__ seq)
{
    const int b = blockIdx.x;
    const int d = threadIdx.x;  // 256 = D
    __shared__ float xs[1500];
    for (int i = d; i < 1500; i += 256) xs[i] = x[(size_t)b * 1500 + i];
    __syncthreads();

    float g = bg[d];
#pragma unroll
    for (int c = 0; c < 16; ++c) g += xs[9 + c] * Wg[d * 16 + c];
    short gb = f2bf(g);
    seq[((size_t)0 * BATCH + b) * 264 + d] = gb;
    seq[((size_t)61 * BATCH + b) * 264 + d] = gb;

    for (int t = 0; t < 60; ++t) {
        float v = bl[d];
#pragma unroll
        for (int c = 0; c < 9; ++c) v += xs[t * 25 + c] * Wl[d * 9 + c];
        seq[((size_t)(t + 1) * BATCH + b) * 264 + d] = f2bf(v);
    }
}

// ---------------- persistent biLSTM layer (unit-split, 256 WGs) ------------
#define LOADW(BUF, kbq)                                                          \
    {                                                                            \
        _Pragma("unroll")                                                        \
        for (int g = 0; g < 4; ++g)                                              \
            BUF[g] = *reinterpret_cast<const short8*>(                           \
                wpb + (size_t)(kbq) * 2048 + g * 512);                           \
    }
#define LOADA(DST, kbg)                                                          \
    {                                                                            \
        DST = ((kbg) < XB)                                                       \
            ? *reinterpret_cast<const short8*>(xs_cur + lr * (XI + 8) + (kbg) * 32 + quad * 8) \
            : *reinterpret_cast<const short8*>(&h_lds[lr][((kbg) - XB) * 32 + quad * 8]); \
    }
#define MFMA4(AV, BUF)                                                           \
    {                                                                            \
        _Pragma("unroll")                                                        \
        for (int g = 0; g < 4; ++g)                                              \
            acc[g] = __builtin_amdgcn_mfma_f32_16x16x32_bf16(                    \
                AV, BUF[g], acc[g], 0, 0, 0);                                    \
    }
#define MFMA4R(AV, i)                                                            \
    {                                                                            \
        _Pragma("unroll")                                                        \
        for (int g = 0; g < 4; ++g)                                              \
            acc[g] = __builtin_amdgcn_mfma_f32_16x16x32_bf16(                    \
                AV, RW[i][g], acc[g], 0, 0, 0);                                  \
    }
// stage one 16-row X tile (XI cols of XSTR-stride rows): 8 waves x 2 rows
#define STAGE(BUFP, T1)                                                          \
    {                                                                            \
        const short* xtb = X + ((size_t)(T1) * BATCH + bbase) * XSTR;            \
        _Pragma("unroll")                                                        \
        for (int i = 0; i < 2; ++i) {                                            \
            int row = wv * 2 + i;                                                \
            if (XI == 512 || lane < 32)                                          \
                load_lds16(xtb + (size_t)row * XSTR + lane * 8,                  \
                           (BUFP) + row * (XI + 8));                             \
        }                                                                        \
    }

template <int KK, int XSTR, int OSTR>  // KK=512: XI=256 (layer0); KK=768: XI=512
__global__ __launch_bounds__(512, 2) void lstm_fused_kernel(
    const short* __restrict__ X,      // (62,1024,XSTR) bf16, first XI cols used
    const short* __restrict__ Wcat,   // unit-split wave-blocked [Wih|Whh]
    const float* __restrict__ bih, const float* __restrict__ bhh,
    short* __restrict__ Hout,         // (62,1024,OSTR); dir d -> cols [256d,..)
    int* __restrict__ flags)          // 128 pairs x 2 halves x 16-int pad
{
    constexpr int XI = KK - 256;
    constexpr int KB = KK / 32;   // 16 or 24
    constexpr int XB = XI / 32;   // 8 or 16
    constexpr int S  = KB - 4;    // streamed blocks 0..S-1; resident S..KB-1

    const int wg    = blockIdx.x;     // 256 = (2 halves) x (2 dirs x 64 tiles)
    const int half  = wg >> 7;
    const int pair  = wg & 127;       // dir*64 + tile
    const int dir   = pair >> 6;
    const int bbase = (pair & 63) * 16;
    const int tid   = threadIdx.x;
    const int wv    = tid >> 6;       // 0..7
    const int lane  = tid & 63;
    const int quad  = lane >> 4;
    const int lr    = lane & 15;

    __shared__ __align__(16) short h_lds[16][264];
    __shared__ __align__(16) short x_stage[2][16 * (XI + 8)];
    __shared__ float bias_sh[1024];
    for (int i = tid; i < 16 * 264; i += 512) (&h_lds[0][0])[i] = 0;
    for (int i = tid; i < 1024; i += 512)
        bias_sh[i] = bih[dir * 1024 + i] + bhh[dir * 1024 + i];

    // per-wave weight stream: KB blocks of 2048 shorts (4 gates x 512)
    const short* wpb = Wcat +
        ((size_t)((dir * 2 + half) * 8 + wv) * KB) * 2048 + lane * 8;

    // register-resident Whh tail: blocks KB-4..KB-1, loaded once (64 VGPR)
    short8 RW[4][4];
#pragma unroll
    for (int i = 0; i < 4; ++i)
#pragma unroll
        for (int g = 0; g < 4; ++g)
            RW[i][g] = *reinterpret_cast<const short8*>(
                wpb + (size_t)(S + i) * 2048 + g * 512);

    const int colC = (half ^ 1) * 128;
    const int myf = ((pair << 1) | half) * 16;        // 64B-padded flags
    const int paf = ((pair << 1) | (half ^ 1)) * 16;

    float c_st[4];
#pragma unroll
    for (int r = 0; r < 4; ++r) c_st[r] = 0.0f;

    // prologue: stage X[t0] into buffer 0 (drained by the barrier below)
    {
        const int t0 = dir ? (TSTEPS - 1) : 0;
        STAGE(&x_stage[0][0], t0);
    }
    __syncthreads();

    for (int st = 0; st < TSTEPS; ++st) {
        const int t = dir ? (TSTEPS - 1 - st) : st;
        if (st + 1 < TSTEPS) {
            const int t1 = dir ? (TSTEPS - 2 - st) : (st + 1);
            STAGE(&x_stage[(st + 1) & 1][0], t1);
        }
        const short* xs_cur = &x_stage[st & 1][0];

        floatx4 acc[4];
#pragma unroll
        for (int i = 0; i < 4; ++i) acc[i] = (floatx4){0.f, 0.f, 0.f, 0.f};

        // streamed part (blocks 0..S-1), dist-2 register pipeline
        short8 W0[4], W1[4], Y0[4], Y1[4], a0, a1;
        LOADW(W0, 0);
        LOADW(W1, 1);
        LOADA(a0, 0);
#pragma unroll 1
        for (int kb = 0; kb < S - 4; kb += 4) {
            LOADW(Y0, kb + 2); LOADA(a1, kb + 1); MFMA4(a0, W0);
            LOADW(Y1, kb + 3); LOADA(a0, kb + 2); MFMA4(a1, W1);
            LOADW(W0, kb + 4); LOADA(a1, kb + 3); MFMA4(a0, Y0);
            LOADW(W1, kb + 5); LOADA(a0, kb + 4); MFMA4(a1, Y1);
        }
        LOADW(Y0, S - 2); LOADA(a1, S - 3); MFMA4(a0, W0);
        LOADW(Y1, S - 1); LOADA(a0, S - 2); MFMA4(a1, W1);
        LOADA(a1, S - 1); MFMA4(a0, Y0);
        MFMA4(a1, Y1);

        // resident tail (blocks S..KB-1): zero weight loads
        LOADA(a0, S + 0);
        LOADA(a1, S + 1); MFMA4R(a0, 0);
        LOADA(a0, S + 2); MFMA4R(a1, 1);
        LOADA(a1, S + 3); MFMA4R(a0, 2);
        MFMA4R(a1, 3);

        __syncthreads();  // (1) all h_lds / x_stage reads of this step done

        // cell update -> own h_lds columns (all 4 gates thread-local)
        {
            const int unit = half * 128 + wv * 16 + lr;
            const float bi  = bias_sh[0 * 256 + unit];
            const float bf_ = bias_sh[1 * 256 + unit];
            const float bg_ = bias_sh[2 * 256 + unit];
            const float bo_ = bias_sh[3 * 256 + unit];
#pragma unroll
            for (int r = 0; r < 4; ++r) {
                float iv = acc[0][r] + bi;
                float fv = acc[1][r] + bf_;
                float gv = acc[2][r] + bg_;
                float ov = acc[3][r] + bo_;
                float c = sigf(fv) * c_st[r] + sigf(iv) * tanhf_fast(gv);
                c_st[r] = c;
                float h = sigf(ov) * tanhf_fast(c);
                h_lds[quad * 4 + r][unit] = f2bf(h);
            }
        }
        __syncthreads();  // (2) own half complete in h_lds

        // own-half writeback: coalesced agent-scope 8B stores (partner reads)
        {
            const int row = tid >> 5, c4 = tid & 31;
            unsigned long long v = *reinterpret_cast<const unsigned long long*>(
                &h_lds[row][half * 128 + c4 * 4]);
            __hip_atomic_store(
                reinterpret_cast<unsigned long long*>(
                    Hout + ((size_t)t * BATCH + bbase + row) * OSTR +
                    dir * 256 + half * 128) + c4,
                v, __ATOMIC_RELAXED, __HIP_MEMORY_SCOPE_AGENT);
        }
        __syncthreads();  // (3) stores drained (vmcnt 0 at coherence point)
                          //     -> flag may be posted RELAXED

        if (st + 1 < TSTEPS) {
            // per-wave handshake: post once (tid0, after the drain barrier --
            // same loose timing as R14/R21), each wave's lane0 polls, then the
            // wave pulls its own 2 rows (in-order issue: pulls retire after
            // the poll load), ds_writes, single trailing barrier.
            if (tid == 0)
                __hip_atomic_store(&flags[myf], st + 1, __ATOMIC_RELAXED,
                                   __HIP_MEMORY_SCOPE_AGENT);
            if (lane == 0) {
                while (__hip_atomic_load(&flags[paf], __ATOMIC_RELAXED,
                                         __HIP_MEMORY_SCOPE_AGENT) <= st)
                    __builtin_amdgcn_s_sleep(1);
            }
            {
                const int row = wv * 2 + (lane >> 5), c4 = lane & 31;
                unsigned long long v = __hip_atomic_load(
                    reinterpret_cast<const unsigned long long*>(
                        Hout + ((size_t)t * BATCH + bbase + row) * OSTR +
                        dir * 256 + colC) + c4,
                    __ATOMIC_RELAXED, __HIP_MEMORY_SCOPE_AGENT);
                *reinterpret_cast<unsigned long long*>(
                    &h_lds[row][colC + c4 * 4]) = v;
            }
            __syncthreads();  // (4') partner half visible to all waves
        }
    }
}

// ---------------- heads (fp32 output; h1 row stride 512) -------------------
__global__ __launch_bounds__(256) void lout_kernel(
    const short* __restrict__ h1, const float* __restrict__ Wlp,
    const float* __restrict__ blp, float* __restrict__ out)
{
    __shared__ float wl[6 * 512];
    for (int i = threadIdx.x; i < 6 * 512; i += 256) wl[i] = Wlp[i];
    __syncthreads();

    int idx = blockIdx.x * 256 + threadIdx.x;
    if (idx >= BATCH * 60) return;
    int b = idx & (BATCH - 1);
    int s = idx >> 10;
    const short* hrow = h1 + ((size_t)(s + 1) * BATCH + b) * 512;

    float acc[6];
#pragma unroll
    for (int j = 0; j < 6; ++j) acc[j] = blp[j];
    for (int k = 0; k < 512; k += 8) {
        short8 hv = *reinterpret_cast<const short8*>(hrow + k);
#pragma unroll
        for (int e = 0; e < 8; ++e) {
            float h = bf2f(hv[e]);
#pragma unroll
            for (int j = 0; j < 6; ++j) acc[j] += h * wl[j * 512 + k + e];
        }
    }
    float* orow = out + ((size_t)b * 60 + s) * 14;
#pragma unroll
    for (int j = 0; j < 6; ++j) orow[j] = acc[j];
}

__global__ __launch_bounds__(256) void gout_kernel(
    const short* __restrict__ h1, const float* __restrict__ Wgp,
    const float* __restrict__ bgp, float* __restrict__ out)
{
    __shared__ float wg[8 * 1024];
    for (int i = threadIdx.x; i < 8 * 1024; i += 256) wg[i] = Wgp[i];
    __syncthreads();

    int b = blockIdx.x * 256 + threadIdx.x;
    if (b >= BATCH) return;
    const short* ha = h1 + (size_t)b * 512;
    const short* hb = h1 + ((size_t)61 * BATCH + b) * 512;

    float acc[8];
#pragma unroll
    for (int j = 0; j < 8; ++j) acc[j] = bgp[j];
    for (int k = 0; k < 512; k += 8) {
        short8 h1v = *reinterpret_cast<const short8*>(ha + k);
        short8 h2v = *reinterpret_cast<const short8*>(hb + k);
#pragma unroll
        for (int e = 0; e < 8; ++e) {
            float v1 = bf2f(h1v[e]);
            float v2 = bf2f(h2v[e]);
#pragma unroll
            for (int j = 0; j < 8; ++j) {
                acc[j] += v1 * wg[j * 1024 + k + e];
                acc[j] += v2 * wg[j * 1024 + 512 + k + e];
            }
        }
    }
    for (int s = 0; s < 60; ++s) {
        float* orow = out + ((size_t)b * 60 + s) * 14 + 6;
#pragma unroll
        for (int j = 0; j < 8; ++j) orow[j] = acc[j];
    }
}

// ---------------- launch ---------------------------------------------------
extern "C" void kernel_launch(void* const* d_in, const int* in_sizes, int n_in,
                              void* d_out, int out_size, void* d_ws, size_t ws_size,
                              hipStream_t stream)
{
    const float* x    = (const float*)d_in[0];
    const float* Wg   = (const float*)d_in[1];
    const float* bg   = (const float*)d_in[2];
    const float* Wl   = (const float*)d_in[3];
    const float* bl   = (const float*)d_in[4];
    const float* Wih0 = (const float*)d_in[5];
    const float* Whh0 = (const float*)d_in[6];
    const float* bih0 = (const float*)d_in[7];
    const float* bhh0 = (const float*)d_in[8];
    const float* Wih1 = (const float*)d_in[9];
    const float* Whh1 = (const float*)d_in[10];
    const float* bih1 = (const float*)d_in[11];
    const float* bhh1 = (const float*)d_in[12];
    const float* Wgp  = (const float*)d_in[13];
    const float* bgp  = (const float*)d_in[14];
    const float* Wlp  = (const float*)d_in[15];
    const float* blp  = (const float*)d_in[16];
    float* out = (float*)d_out;

    const size_t seq_e = (size_t)TSTEPS * BATCH * 264;  // 16,760,832 (stride 264)
    const size_t h0_e  = (size_t)TSTEPS * BATCH * 520;  // 33,013,760 (stride 520)
    const size_t h1_e  = (size_t)TSTEPS * BATCH * 512;  // 32,505,856 (stride 512)
    const size_t cat_e = 8 * 24 * 8192;                 //  1,572,864 (shared, max)
    const size_t cat0_n = 8 * 16 * 8192;                //  layer0 repack count

    short* seq = (short*)d_ws;
    short* h0  = seq + seq_e;
    short* h1  = h0 + h0_e;
    short* cat = h1 + h1_e;
    int*   flags = (int*)(cat + cat_e);   // 2 layers x 256 flags x 16-int pad
    const size_t need = (seq_e + h0_e + h1_e + cat_e) * sizeof(short) + 65536;
    if (ws_size < need) return;

    hipMemsetAsync(flags, 0, 2 * 256 * 16 * sizeof(int), stream);

    embed_kernel<<<BATCH, 256, 0, stream>>>(x, Wg, bg, Wl, bl, seq);

    repack_kernel<<<(int)((cat0_n + 255) / 256), 256, 0, stream>>>(Wih0, Whh0, cat, 256);
    lstm_fused_kernel<512, 264, 520><<<256, 512, 0, stream>>>(seq, cat, bih0, bhh0, h0, flags);

    repack_kernel<<<(int)((cat_e + 255) / 256), 256, 0, stream>>>(Wih1, Whh1, cat, 512);
    lstm_fused_kernel<768, 520, 512><<<256, 512, 0, stream>>>(h0, cat, bih1, bhh1, h1, flags + 256 * 16);

    lout_kernel<<<(BATCH * 60 + 255) / 256, 256, 0, stream>>>(h1, Wlp, blp, out);
    gout_kernel<<<(BATCH + 255) / 256, 256, 0, stream>>>(h1, Wgp, bgp, out);
}

// Round 13
// 839.273 us; speedup vs baseline: 1.2732x; 1.1345x over previous
//
#include <hip/hip_runtime.h>
#include <hip/hip_bf16.h>
#include <cstdint>
#include <cstddef>

// Model: B=1024, S=60, CIN=25, D=256, H=256, T=S+2=62
// Inputs fp32, output fp32; internal bf16 activations/weights, fp32 accum.
//
// Round-24 = R23 (952us verified) + ONE change: gout parallelization.
// Old gout ran 4 WGs (1024 threads) -- each thread a serial 1024-FMA dot +
// 60 scattered 32B stores; est. ~100us of the ~215us non-lstm remainder.
// New: gout_acc (32 blocks, thread=(b,j), per-(b,j) loop BIT-IDENTICAL in
// order to the old per-thread j-lane; gacc stored in the dead seq region --
// zero new workspace, we sit at the proven 167.77MB edge) + gout_bcast
// (1920 blocks, fully parallel 60-way broadcast write).
// Session rules: weights NEVER via LDS (R12/R16 3x collapse); exchange
// loose vs writes (R15 storm); RELAXED handshake only (R19); resident
// Whh dose = 4 exactly (R20 miscompile / R22 L2-thrash); one change/round.

typedef __attribute__((ext_vector_type(8))) short short8;
typedef __attribute__((ext_vector_type(4))) float floatx4;

#define BATCH 1024
#define TSTEPS 62

__device__ __forceinline__ float bf2f(short s) {
    union { unsigned u; float f; } v;
    v.u = ((unsigned)(unsigned short)s) << 16;
    return v.f;
}
__device__ __forceinline__ short f2bf(float f) {
    union { float f; unsigned u; } v; v.f = f;
    unsigned r = (v.u + 0x7fffu + ((v.u >> 16) & 1u)) >> 16;  // RNE
    return (short)r;
}
__device__ __forceinline__ float sigf(float x) {
    return __builtin_amdgcn_rcpf(1.0f + __expf(-x));
}
__device__ __forceinline__ float tanhf_fast(float x) {
    return 2.0f * __builtin_amdgcn_rcpf(1.0f + __expf(-2.0f * x)) - 1.0f;
}

// async 16B/lane global->LDS (LDS dest = uniform base + lane*16)
__device__ __forceinline__ void load_lds16(const short* g, short* l) {
    __builtin_amdgcn_global_load_lds(
        (const __attribute__((address_space(1))) void*)g,
        (__attribute__((address_space(3))) void*)l, 16, 0, 0);
}

// ------------- repack [Wih|Whh] into unit-split wave-blocked layout --------
// dst idx = ((((dh*8 + w)*KB + kb)*4 + g)*64 + lane)*8 + j
//   dh = dir*2 + half
//   row = g*256 + half*128 + w*16 + (lane&15)
//   k   = kb*32 + (lane>>4)*8 + j
__global__ __launch_bounds__(256) void repack_kernel(
    const float* __restrict__ Wih, const float* __restrict__ Whh,
    short* __restrict__ Wp, int XI)
{
    const int KB = (XI + 256) / 32;
    int idx = blockIdx.x * 256 + threadIdx.x;
    if (idx >= 8 * KB * 8192) return;
    int j    = idx & 7;
    int lane = (idx >> 3) & 63;
    int g    = (idx >> 9) & 3;
    int rem  = idx >> 11;
    int kb   = rem % KB;
    int rem2 = rem / KB;
    int w    = rem2 & 7;
    int dh   = rem2 >> 3;       // 0..3
    int dir  = dh >> 1;
    int half = dh & 1;
    int row  = g * 256 + half * 128 + w * 16 + (lane & 15);
    int k    = kb * 32 + (lane >> 4) * 8 + j;
    float v = (k < XI) ? Wih[((size_t)dir * 1024 + row) * XI + k]
                       : Whh[((size_t)dir * 1024 + row) * 256 + (k - XI)];
    Wp[idx] = f2bf(v);
}

// ---------------- embed: seq[t][b][d], row stride 264 ----------------------
__global__ __launch_bounds__(256) void embed_kernel(
    const float* __restrict__ x, const float* __restrict__ Wg,
    const float* __restrict__ bg, const float* __restrict__ Wl,
    const float* __restrict__ bl, short* __restrict__ seq)
{
    const int b = blockIdx.x;
    const int d = threadIdx.x;  // 256 = D
    __shared__ float xs[1500];
    for (int i = d; i < 1500; i += 256) xs[i] = x[(size_t)b * 1500 + i];
    __syncthreads();

    float g = bg[d];
#pragma unroll
    for (int c = 0; c < 16; ++c) g += xs[9 + c] * Wg[d * 16 + c];
    short gb = f2bf(g);
    seq[((size_t)0 * BATCH + b) * 264 + d] = gb;
    seq[((size_t)61 * BATCH + b) * 264 + d] = gb;

    for (int t = 0; t < 60; ++t) {
        float v = bl[d];
#pragma unroll
        for (int c = 0; c < 9; ++c) v += xs[t * 25 + c] * Wl[d * 9 + c];
        seq[((size_t)(t + 1) * BATCH + b) * 264 + d] = f2bf(v);
    }
}

// ---------------- persistent biLSTM layer (unit-split, 256 WGs) ------------
#define LOADW(BUF, kbq)                                                          \
    {                                                                            \
        _Pragma("unroll")                                                        \
        for (int g = 0; g < 4; ++g)                                              \
            BUF[g] = *reinterpret_cast<const short8*>(                           \
                wpb + (size_t)(kbq) * 2048 + g * 512);                           \
    }
#define LOADA(DST, kbg)                                                          \
    {                                                                            \
        DST = ((kbg) < XB)                                                       \
            ? *reinterpret_cast<const short8*>(xs_cur + lr * (XI + 8) + (kbg) * 32 + quad * 8) \
            : *reinterpret_cast<const short8*>(&h_lds[lr][((kbg) - XB) * 32 + quad * 8]); \
    }
#define MFMA4(AV, BUF)                                                           \
    {                                                                            \
        _Pragma("unroll")                                                        \
        for (int g = 0; g < 4; ++g)                                              \
            acc[g] = __builtin_amdgcn_mfma_f32_16x16x32_bf16(                    \
                AV, BUF[g], acc[g], 0, 0, 0);                                    \
    }
#define MFMA4R(AV, i)                                                            \
    {                                                                            \
        _Pragma("unroll")                                                        \
        for (int g = 0; g < 4; ++g)                                              \
            acc[g] = __builtin_amdgcn_mfma_f32_16x16x32_bf16(                    \
                AV, RW[i][g], acc[g], 0, 0, 0);                                  \
    }
// stage one 16-row X tile (XI cols of XSTR-stride rows): 8 waves x 2 rows
#define STAGE(BUFP, T1)                                                          \
    {                                                                            \
        const short* xtb = X + ((size_t)(T1) * BATCH + bbase) * XSTR;            \
        _Pragma("unroll")                                                        \
        for (int i = 0; i < 2; ++i) {                                            \
            int row = wv * 2 + i;                                                \
            if (XI == 512 || lane < 32)                                          \
                load_lds16(xtb + (size_t)row * XSTR + lane * 8,                  \
                           (BUFP) + row * (XI + 8));                             \
        }                                                                        \
    }

template <int KK, int XSTR, int OSTR>  // KK=512: XI=256 (layer0); KK=768: XI=512
__global__ __launch_bounds__(512, 2) void lstm_fused_kernel(
    const short* __restrict__ X,      // (62,1024,XSTR) bf16, first XI cols used
    const short* __restrict__ Wcat,   // unit-split wave-blocked [Wih|Whh]
    const float* __restrict__ bih, const float* __restrict__ bhh,
    short* __restrict__ Hout,         // (62,1024,OSTR); dir d -> cols [256d,..)
    int* __restrict__ flags)          // 128 pairs x 2 halves x 16-int pad
{
    constexpr int XI = KK - 256;
    constexpr int KB = KK / 32;   // 16 or 24
    constexpr int XB = XI / 32;   // 8 or 16
    constexpr int S  = KB - 4;    // streamed blocks 0..S-1; resident S..KB-1

    const int wg    = blockIdx.x;     // 256 = (2 halves) x (2 dirs x 64 tiles)
    const int half  = wg >> 7;
    const int pair  = wg & 127;       // dir*64 + tile
    const int dir   = pair >> 6;
    const int bbase = (pair & 63) * 16;
    const int tid   = threadIdx.x;
    const int wv    = tid >> 6;       // 0..7
    const int lane  = tid & 63;
    const int quad  = lane >> 4;
    const int lr    = lane & 15;

    __shared__ __align__(16) short h_lds[16][264];
    __shared__ __align__(16) short x_stage[2][16 * (XI + 8)];
    __shared__ float bias_sh[1024];
    for (int i = tid; i < 16 * 264; i += 512) (&h_lds[0][0])[i] = 0;
    for (int i = tid; i < 1024; i += 512)
        bias_sh[i] = bih[dir * 1024 + i] + bhh[dir * 1024 + i];

    // per-wave weight stream: KB blocks of 2048 shorts (4 gates x 512)
    const short* wpb = Wcat +
        ((size_t)((dir * 2 + half) * 8 + wv) * KB) * 2048 + lane * 8;

    // register-resident Whh tail: blocks KB-4..KB-1, loaded once (64 VGPR)
    short8 RW[4][4];
#pragma unroll
    for (int i = 0; i < 4; ++i)
#pragma unroll
        for (int g = 0; g < 4; ++g)
            RW[i][g] = *reinterpret_cast<const short8*>(
                wpb + (size_t)(S + i) * 2048 + g * 512);

    const int colC = (half ^ 1) * 128;
    const int myf = ((pair << 1) | half) * 16;        // 64B-padded flags
    const int paf = ((pair << 1) | (half ^ 1)) * 16;

    float c_st[4];
#pragma unroll
    for (int r = 0; r < 4; ++r) c_st[r] = 0.0f;

    // prologue: stage X[t0] into buffer 0 (drained by the barrier below)
    {
        const int t0 = dir ? (TSTEPS - 1) : 0;
        STAGE(&x_stage[0][0], t0);
    }
    __syncthreads();

    for (int st = 0; st < TSTEPS; ++st) {
        const int t = dir ? (TSTEPS - 1 - st) : st;
        if (st + 1 < TSTEPS) {
            const int t1 = dir ? (TSTEPS - 2 - st) : (st + 1);
            STAGE(&x_stage[(st + 1) & 1][0], t1);
        }
        const short* xs_cur = &x_stage[st & 1][0];

        floatx4 acc[4];
#pragma unroll
        for (int i = 0; i < 4; ++i) acc[i] = (floatx4){0.f, 0.f, 0.f, 0.f};

        // streamed part (blocks 0..S-1), dist-2 register pipeline
        short8 W0[4], W1[4], Y0[4], Y1[4], a0, a1;
        LOADW(W0, 0);
        LOADW(W1, 1);
        LOADA(a0, 0);
#pragma unroll 1
        for (int kb = 0; kb < S - 4; kb += 4) {
            LOADW(Y0, kb + 2); LOADA(a1, kb + 1); MFMA4(a0, W0);
            LOADW(Y1, kb + 3); LOADA(a0, kb + 2); MFMA4(a1, W1);
            LOADW(W0, kb + 4); LOADA(a1, kb + 3); MFMA4(a0, Y0);
            LOADW(W1, kb + 5); LOADA(a0, kb + 4); MFMA4(a1, Y1);
        }
        LOADW(Y0, S - 2); LOADA(a1, S - 3); MFMA4(a0, W0);
        LOADW(Y1, S - 1); LOADA(a0, S - 2); MFMA4(a1, W1);
        LOADA(a1, S - 1); MFMA4(a0, Y0);
        MFMA4(a1, Y1);

        // resident tail (blocks S..KB-1): zero weight loads
        LOADA(a0, S + 0);
        LOADA(a1, S + 1); MFMA4R(a0, 0);
        LOADA(a0, S + 2); MFMA4R(a1, 1);
        LOADA(a1, S + 3); MFMA4R(a0, 2);
        MFMA4R(a1, 3);

        __syncthreads();  // (1) all h_lds / x_stage reads of this step done

        // cell update -> own h_lds columns (all 4 gates thread-local)
        {
            const int unit = half * 128 + wv * 16 + lr;
            const float bi  = bias_sh[0 * 256 + unit];
            const float bf_ = bias_sh[1 * 256 + unit];
            const float bg_ = bias_sh[2 * 256 + unit];
            const float bo_ = bias_sh[3 * 256 + unit];
#pragma unroll
            for (int r = 0; r < 4; ++r) {
                float iv = acc[0][r] + bi;
                float fv = acc[1][r] + bf_;
                float gv = acc[2][r] + bg_;
                float ov = acc[3][r] + bo_;
                float c = sigf(fv) * c_st[r] + sigf(iv) * tanhf_fast(gv);
                c_st[r] = c;
                float h = sigf(ov) * tanhf_fast(c);
                h_lds[quad * 4 + r][unit] = f2bf(h);
            }
        }
        __syncthreads();  // (2) own half complete in h_lds

        // own-half writeback: coalesced agent-scope 8B stores (partner reads)
        {
            const int row = tid >> 5, c4 = tid & 31;
            unsigned long long v = *reinterpret_cast<const unsigned long long*>(
                &h_lds[row][half * 128 + c4 * 4]);
            __hip_atomic_store(
                reinterpret_cast<unsigned long long*>(
                    Hout + ((size_t)t * BATCH + bbase + row) * OSTR +
                    dir * 256 + half * 128) + c4,
                v, __ATOMIC_RELAXED, __HIP_MEMORY_SCOPE_AGENT);
        }
        __syncthreads();  // (3) stores drained (vmcnt 0 at coherence point)
                          //     -> flag may be posted RELAXED

        if (st + 1 < TSTEPS) {
            // per-wave handshake: post once (tid0, after the drain barrier --
            // same loose timing as R14/R21), each wave's lane0 polls, then the
            // wave pulls its own 2 rows (in-order issue: pulls retire after
            // the poll load), ds_writes, single trailing barrier.
            if (tid == 0)
                __hip_atomic_store(&flags[myf], st + 1, __ATOMIC_RELAXED,
                                   __HIP_MEMORY_SCOPE_AGENT);
            if (lane == 0) {
                while (__hip_atomic_load(&flags[paf], __ATOMIC_RELAXED,
                                         __HIP_MEMORY_SCOPE_AGENT) <= st)
                    __builtin_amdgcn_s_sleep(1);
            }
            {
                const int row = wv * 2 + (lane >> 5), c4 = lane & 31;
                unsigned long long v = __hip_atomic_load(
                    reinterpret_cast<const unsigned long long*>(
                        Hout + ((size_t)t * BATCH + bbase + row) * OSTR +
                        dir * 256 + colC) + c4,
                    __ATOMIC_RELAXED, __HIP_MEMORY_SCOPE_AGENT);
                *reinterpret_cast<unsigned long long*>(
                    &h_lds[row][colC + c4 * 4]) = v;
            }
            __syncthreads();  // (4') partner half visible to all waves
        }
    }
}

// ---------------- heads (fp32 output; h1 row stride 512) -------------------
__global__ __launch_bounds__(256) void lout_kernel(
    const short* __restrict__ h1, const float* __restrict__ Wlp,
    const float* __restrict__ blp, float* __restrict__ out)
{
    __shared__ float wl[6 * 512];
    for (int i = threadIdx.x; i < 6 * 512; i += 256) wl[i] = Wlp[i];
    __syncthreads();

    int idx = blockIdx.x * 256 + threadIdx.x;
    if (idx >= BATCH * 60) return;
    int b = idx & (BATCH - 1);
    int s = idx >> 10;
    const short* hrow = h1 + ((size_t)(s + 1) * BATCH + b) * 512;

    float acc[6];
#pragma unroll
    for (int j = 0; j < 6; ++j) acc[j] = blp[j];
    for (int k = 0; k < 512; k += 8) {
        short8 hv = *reinterpret_cast<const short8*>(hrow + k);
#pragma unroll
        for (int e = 0; e < 8; ++e) {
            float h = bf2f(hv[e]);
#pragma unroll
            for (int j = 0; j < 6; ++j) acc[j] += h * wl[j * 512 + k + e];
        }
    }
    float* orow = out + ((size_t)b * 60 + s) * 14;
#pragma unroll
    for (int j = 0; j < 6; ++j) orow[j] = acc[j];
}

// gout split: acc kernel (32 blocks, thread=(b,j)) -- per-(b,j) accumulation
// order BIT-IDENTICAL to the old gout's j-lane; result to gacc[b*8+j].
__global__ __launch_bounds__(256) void gout_acc_kernel(
    const short* __restrict__ h1, const float* __restrict__ Wgp,
    const float* __restrict__ bgp, float* __restrict__ gacc)
{
    __shared__ float wg[8 * 1024];
    for (int i = threadIdx.x; i < 8 * 1024; i += 256) wg[i] = Wgp[i];
    __syncthreads();

    int idx = blockIdx.x * 256 + threadIdx.x;   // 8192 total
    int b = idx >> 3;
    int j = idx & 7;
    const short* ha = h1 + (size_t)b * 512;
    const short* hb = h1 + ((size_t)61 * BATCH + b) * 512;

    float acc = bgp[j];
    for (int k = 0; k < 512; k += 8) {
        short8 h1v = *reinterpret_cast<const short8*>(ha + k);
        short8 h2v = *reinterpret_cast<const short8*>(hb + k);
#pragma unroll
        for (int e = 0; e < 8; ++e) {
            acc += bf2f(h1v[e]) * wg[j * 1024 + k + e];
            acc += bf2f(h2v[e]) * wg[j * 1024 + 512 + k + e];
        }
    }
    gacc[b * 8 + j] = acc;
}

// gout split: broadcast kernel -- fully parallel 60-way write.
__global__ __launch_bounds__(256) void gout_bcast_kernel(
    const float* __restrict__ gacc, float* __restrict__ out)
{
    int idx = blockIdx.x * 256 + threadIdx.x;   // 1024*60*8 total
    if (idx >= BATCH * 60 * 8) return;
    int j = idx & 7;
    int s = (idx >> 3) % 60;
    int b = idx / 480;
    out[((size_t)b * 60 + s) * 14 + 6 + j] = gacc[b * 8 + j];
}

// ---------------- launch ---------------------------------------------------
extern "C" void kernel_launch(void* const* d_in, const int* in_sizes, int n_in,
                              void* d_out, int out_size, void* d_ws, size_t ws_size,
                              hipStream_t stream)
{
    const float* x    = (const float*)d_in[0];
    const float* Wg   = (const float*)d_in[1];
    const float* bg   = (const float*)d_in[2];
    const float* Wl   = (const float*)d_in[3];
    const float* bl   = (const float*)d_in[4];
    const float* Wih0 = (const float*)d_in[5];
    const float* Whh0 = (const float*)d_in[6];
    const float* bih0 = (const float*)d_in[7];
    const float* bhh0 = (const float*)d_in[8];
    const float* Wih1 = (const float*)d_in[9];
    const float* Whh1 = (const float*)d_in[10];
    const float* bih1 = (const float*)d_in[11];
    const float* bhh1 = (const float*)d_in[12];
    const float* Wgp  = (const float*)d_in[13];
    const float* bgp  = (const float*)d_in[14];
    const float* Wlp  = (const float*)d_in[15];
    const float* blp  = (const float*)d_in[16];
    float* out = (float*)d_out;

    const size_t seq_e = (size_t)TSTEPS * BATCH * 264;  // 16,760,832 (stride 264)
    const size_t h0_e  = (size_t)TSTEPS * BATCH * 520;  // 33,013,760 (stride 520)
    const size_t h1_e  = (size_t)TSTEPS * BATCH * 512;  // 32,505,856 (stride 512)
    const size_t cat_e = 8 * 24 * 8192;                 //  1,572,864 (shared, max)
    const size_t cat0_n = 8 * 16 * 8192;                //  layer0 repack count

    short* seq = (short*)d_ws;
    short* h0  = seq + seq_e;
    short* h1  = h0 + h0_e;
    short* cat = h1 + h1_e;
    int*   flags = (int*)(cat + cat_e);   // 2 layers x 256 flags x 16-int pad
    float* gacc  = (float*)seq;           // reuses dead seq region post-lstm0
    const size_t need = (seq_e + h0_e + h1_e + cat_e) * sizeof(short) + 65536;
    if (ws_size < need) return;

    hipMemsetAsync(flags, 0, 2 * 256 * 16 * sizeof(int), stream);

    embed_kernel<<<BATCH, 256, 0, stream>>>(x, Wg, bg, Wl, bl, seq);

    repack_kernel<<<(int)((cat0_n + 255) / 256), 256, 0, stream>>>(Wih0, Whh0, cat, 256);
    lstm_fused_kernel<512, 264, 520><<<256, 512, 0, stream>>>(seq, cat, bih0, bhh0, h0, flags);

    repack_kernel<<<(int)((cat_e + 255) / 256), 256, 0, stream>>>(Wih1, Whh1, cat, 512);
    lstm_fused_kernel<768, 520, 512><<<256, 512, 0, stream>>>(h0, cat, bih1, bhh1, h1, flags + 256 * 16);

    lout_kernel<<<(BATCH * 60 + 255) / 256, 256, 0, stream>>>(h1, Wlp, blp, out);
    gout_acc_kernel<<<32, 256, 0, stream>>>(h1, Wgp, bgp, gacc);
    gout_bcast_kernel<<<(BATCH * 60 * 8 + 255) / 256, 256, 0, stream>>>(gacc, out);
}